// Round 1
// baseline (7354.086 us; speedup 1.0000x reference)
//
#include <hip/hip_runtime.h>

#define NT 256

static constexpr int FA  = 64;
static constexpr int FS  = 256;
static constexpr int HID = 1024;
static constexpr int TT  = 64;
static constexpr int KX  = FA + FS;   // 320
static constexpr int BR  = 16;        // batch rows per block

__device__ __forceinline__ void gll16(const void* g, void* l) {
  __builtin_amdgcn_global_load_lds(
      (const __attribute__((address_space(1))) unsigned int*)g,
      (__attribute__((address_space(3))) unsigned int*)l, 16, 0, 0);
}
__device__ __forceinline__ void gll4(const void* g, void* l) {
  __builtin_amdgcn_global_load_lds(
      (const __attribute__((address_space(1))) unsigned int*)g,
      (__attribute__((address_space(3))) unsigned int*)l, 4, 0, 0);
}

__device__ __forceinline__ float tanh_fast(float a) {
  float e = __expf(2.0f * a);          // inf for large a -> returns +/-1 exactly
  return 1.0f - __fdividef(2.0f, e + 1.0f);
}

extern "C" __global__ void __launch_bounds__(NT, 1)
ode_kernel(const float* __restrict__ actions, const float* __restrict__ y0,
           const float* __restrict__ W1, const float* __restrict__ b1,
           const float* __restrict__ W2, const float* __restrict__ b2,
           const float* __restrict__ dtp, float* __restrict__ out)
{
  // LDS: 20K x + 64K h + 64K stage + 4K b1 + 1K b2 = 153 KB -> 1 block/CU
  __shared__ __align__(16) float xs[BR][KX];       // x = [a(64) | y(256)] per row
  __shared__ __align__(16) float hs[BR * HID];     // h; reused as partial buf [4][4096]
  __shared__ __align__(16) float stg[2 * 8 * HID]; // weight panels, double buffered
  __shared__ __align__(16) float b1s[HID];
  __shared__ __align__(16) float b2s[FS];

  const int tid  = threadIdx.x;
  const int wave = tid >> 6, lane = tid & 63;
  const int rg   = tid >> 7, cg  = tid & 127;        // GEMM1: 2 rowgrp x 128 colgrp
  const int g2   = tid >> 6, rg2 = (tid >> 5) & 1, cg2 = tid & 31; // GEMM2: 4 k-groups
  const int b0   = blockIdx.x * BR;
  const float dt = dtp[0];

  for (int i = tid; i < HID; i += NT) b1s[i] = b1[i];
  b2s[tid] = b2[tid];

  // init y tile into xs[:,64:] and write out[:, :, 0]
  #pragma unroll
  for (int i = 0; i < BR; ++i) {
    int o = tid + NT * i;
    int r = o >> 8, c = o & 255;
    float v = y0[(b0 + r) * FS + c];
    xs[r][FA + c] = v;
    out[((size_t)((b0 + r) * FS + c)) * TT] = v;
  }

  for (int t = 0; t < TT - 1; ++t) {
    // ---- actions(:, :, t) -> xs[:, 0:64] (direct-to-LDS, per-lane global addr)
    #pragma unroll
    for (int i = 0; i < 4; ++i) {
      int r = i * 4 + wave;
      gll4(actions + ((b0 + r) * FA + lane) * TT + t, &xs[r][0]);
    }
    // ---- prologue: stage W1 panel 0 into stg[0]
    #pragma unroll
    for (int i = 0; i < 8; ++i) {
      int off = (i * 4 + wave) * 256;
      gll16(W1 + off + lane * 4, stg + off);
    }
    __syncthreads();  // drains vmcnt: a-loads + panel 0 complete, y from prev step visible

    // ============ GEMM1: h = tanh(x @ W1 + b1), 8x8 regs/thread ============
    float acc[8][8];
    {
      float4 bA = *(const float4*)&b1s[cg * 8];
      float4 bB = *(const float4*)&b1s[cg * 8 + 4];
      #pragma unroll
      for (int i = 0; i < 8; ++i) {
        acc[i][0]=bA.x; acc[i][1]=bA.y; acc[i][2]=bA.z; acc[i][3]=bA.w;
        acc[i][4]=bB.x; acc[i][5]=bB.y; acc[i][6]=bB.z; acc[i][7]=bB.w;
      }
    }
    for (int p = 0; p < 40; ++p) {
      const int bsel = p & 1;
      if (p < 39) {  // stage next 8-row panel into the other buffer
        const float* src = W1 + (p + 1) * 8 * HID;
        float* dst = stg + (bsel ^ 1) * 8192;
        #pragma unroll
        for (int i = 0; i < 8; ++i) {
          int off = (i * 4 + wave) * 256;
          gll16(src + off + lane * 4, dst + off);
        }
      }
      const float* wp = stg + bsel * 8192;
      const int k0 = p * 8;
      #pragma unroll
      for (int q = 0; q < 2; ++q) {
        float4 xa[8];  // wave-uniform broadcast reads
        #pragma unroll
        for (int i = 0; i < 8; ++i)
          xa[i] = *(const float4*)&xs[rg * 8 + i][k0 + q * 4];
        #pragma unroll
        for (int kk = 0; kk < 4; ++kk) {
          float4 wA = *(const float4*)&wp[(q * 4 + kk) * HID + cg * 8];
          float4 wB = *(const float4*)&wp[(q * 4 + kk) * HID + cg * 8 + 4];
          #pragma unroll
          for (int i = 0; i < 8; ++i) {
            float xv = (kk == 0) ? xa[i].x : (kk == 1) ? xa[i].y
                     : (kk == 2) ? xa[i].z : xa[i].w;
            acc[i][0] += xv * wA.x; acc[i][1] += xv * wA.y;
            acc[i][2] += xv * wA.z; acc[i][3] += xv * wA.w;
            acc[i][4] += xv * wB.x; acc[i][5] += xv * wB.y;
            acc[i][6] += xv * wB.z; acc[i][7] += xv * wB.w;
          }
        }
      }
      __syncthreads();
    }
    // tanh -> hs
    #pragma unroll
    for (int i = 0; i < 8; ++i) {
      float4 h0, h1;
      h0.x = tanh_fast(acc[i][0]); h0.y = tanh_fast(acc[i][1]);
      h0.z = tanh_fast(acc[i][2]); h0.w = tanh_fast(acc[i][3]);
      h1.x = tanh_fast(acc[i][4]); h1.y = tanh_fast(acc[i][5]);
      h1.z = tanh_fast(acc[i][6]); h1.w = tanh_fast(acc[i][7]);
      *(float4*)&hs[(rg * 8 + i) * HID + cg * 8]     = h0;
      *(float4*)&hs[(rg * 8 + i) * HID + cg * 8 + 4] = h1;
    }
    // prologue: stage W2 panel 0 (rows {g*256..+8} for each k-group)
    #pragma unroll
    for (int g = 0; g < 4; ++g) {
      const float* src = W2 + (g * 256) * FS;
      float* dst = stg + g * 2048;
      #pragma unroll
      for (int i = 0; i < 2; ++i) {
        int off = (i * 4 + wave) * 256;
        gll16(src + off + lane * 4, dst + off);
      }
    }
    __syncthreads();  // h visible + W2 panel 0 staged

    // ============ GEMM2: y += dt*(h @ W2 + b2), k-split into 4 groups ============
    float a2[8][8];
    #pragma unroll
    for (int i = 0; i < 8; ++i)
      #pragma unroll
      for (int j = 0; j < 8; ++j) a2[i][j] = 0.f;
    for (int p = 0; p < 32; ++p) {
      const int bsel = p & 1;
      if (p < 31) {
        #pragma unroll
        for (int g = 0; g < 4; ++g) {
          const float* src = W2 + (g * 256 + (p + 1) * 8) * FS;
          float* dst = stg + (bsel ^ 1) * 8192 + g * 2048;
          #pragma unroll
          for (int i = 0; i < 2; ++i) {
            int off = (i * 4 + wave) * 256;
            gll16(src + off + lane * 4, dst + off);
          }
        }
      }
      const float* wp = stg + bsel * 8192 + g2 * 2048;
      const int k0 = g2 * 256 + p * 8;
      #pragma unroll
      for (int q = 0; q < 2; ++q) {
        float4 ha[8];
        #pragma unroll
        for (int i = 0; i < 8; ++i)
          ha[i] = *(const float4*)&hs[(rg2 * 8 + i) * HID + k0 + q * 4];
        #pragma unroll
        for (int kk = 0; kk < 4; ++kk) {
          float4 wA = *(const float4*)&wp[(q * 4 + kk) * FS + cg2 * 8];
          float4 wB = *(const float4*)&wp[(q * 4 + kk) * FS + cg2 * 8 + 4];
          #pragma unroll
          for (int i = 0; i < 8; ++i) {
            float xv = (kk == 0) ? ha[i].x : (kk == 1) ? ha[i].y
                     : (kk == 2) ? ha[i].z : ha[i].w;
            a2[i][0] += xv * wA.x; a2[i][1] += xv * wA.y;
            a2[i][2] += xv * wA.z; a2[i][3] += xv * wA.w;
            a2[i][4] += xv * wB.x; a2[i][5] += xv * wB.y;
            a2[i][6] += xv * wB.z; a2[i][7] += xv * wB.w;
          }
        }
      }
      __syncthreads();
    }
    // write per-group partials into hs (h is dead now; last loop barrier synced all)
    #pragma unroll
    for (int i = 0; i < 8; ++i) {
      *(float4*)&hs[g2 * 4096 + (rg2 * 8 + i) * FS + cg2 * 8] =
          make_float4(a2[i][0], a2[i][1], a2[i][2], a2[i][3]);
      *(float4*)&hs[g2 * 4096 + (rg2 * 8 + i) * FS + cg2 * 8 + 4] =
          make_float4(a2[i][4], a2[i][5], a2[i][6], a2[i][7]);
    }
    __syncthreads();
    // reduce 4 partials, Euler update, store out[:, :, t+1]
    #pragma unroll
    for (int i = 0; i < BR; ++i) {
      int o = tid + NT * i;
      int r = o >> 8, c = o & 255;
      float s = hs[o] + hs[4096 + o] + hs[8192 + o] + hs[12288 + o];
      float yv = xs[r][FA + c] + dt * (s + b2s[c]);
      xs[r][FA + c] = yv;
      out[((size_t)((b0 + r) * FS + c)) * TT + (t + 1)] = yv;
    }
    // no trailing barrier needed: next step's prologue barrier orders xs y-reads,
    // and stg[0] was last read at p=30, h at p=31 (both behind barriers).
  }
}

extern "C" void kernel_launch(void* const* d_in, const int* in_sizes, int n_in,
                              void* d_out, int out_size, void* d_ws, size_t ws_size,
                              hipStream_t stream) {
  const float* actions = (const float*)d_in[1];
  const float* y0      = (const float*)d_in[2];
  const float* W1      = (const float*)d_in[3];
  const float* b1      = (const float*)d_in[4];
  const float* W2      = (const float*)d_in[5];
  const float* b2      = (const float*)d_in[6];
  const float* dtp     = (const float*)d_in[7];
  float* out = (float*)d_out;
  hipLaunchKernelGGL(ode_kernel, dim3(4096 / BR), dim3(NT), 0, stream,
                     actions, y0, W1, b1, W2, b2, dtp, out);
}

// Round 2
// 5506.244 us; speedup vs baseline: 1.3356x; 1.3356x over previous
//
#include <hip/hip_runtime.h>

typedef _Float16 v8h __attribute__((ext_vector_type(8)));
typedef float v4f __attribute__((ext_vector_type(4)));

#define NT 512
static constexpr int BR = 16;   // batch rows per block

// ws half-plane offsets (in _Float16 elements)
static constexpr int W1H_OFF = 0;        // [80 panels][128 n][32 k]
static constexpr int W1L_OFF = 327680;
static constexpr int W2H_OFF = 655360;   // [64 panels][128 n][32 k]
static constexpr int W2L_OFF = 917504;   // total 1,179,648 halves = 2.25 MB

__device__ __forceinline__ void gll16(const void* g, void* l) {
  __builtin_amdgcn_global_load_lds(
      (const __attribute__((address_space(1))) unsigned int*)g,
      (__attribute__((address_space(3))) unsigned int*)l, 16, 0, 0);
}

__device__ __forceinline__ float tanh_fast(float a) {
  float e = __expf(2.0f * a);          // inf for large a -> +/-1 exactly
  return 1.0f - __fdividef(2.0f, e + 1.0f);
}

// One-shot: split W1,W2 into fp16 hi/lo, transposed+panelized for linear staging.
// W1 panel gp = ph*10+p holds W1[p*32+k][ph*128+n]; W2 panel ph2*32+p holds W2[p*32+k][ph2*128+n].
extern "C" __global__ void conv_kernel(const float* __restrict__ W1,
                                       const float* __restrict__ W2,
                                       _Float16* __restrict__ ws) {
  int i = blockIdx.x * 256 + threadIdx.x;
  if (i < 327680) {
    int panel = i >> 12, r = i & 4095;
    int n = r >> 5, k = r & 31;
    int ph = panel / 10, p = panel % 10;
    float w = W1[(p * 32 + k) * 1024 + ph * 128 + n];
    _Float16 h = (_Float16)w;
    ws[W1H_OFF + i] = h;
    ws[W1L_OFF + i] = (_Float16)((w - (float)h) * 2048.f);
  } else {
    int j = i - 327680;
    if (j < 262144) {
      int panel = j >> 12, r = j & 4095;
      int n = r >> 5, k = r & 31;
      int ph = panel / 32, p = panel % 32;
      float w = W2[(p * 32 + k) * 256 + ph * 128 + n];
      _Float16 h = (_Float16)w;
      ws[W2H_OFF + j] = h;
      ws[W2L_OFF + j] = (_Float16)((w - (float)h) * 2048.f);
    }
  }
}

// stage one 16 KB panel (4096 hi + 4096 lo halves) into stg buffer
__device__ __forceinline__ void stage_panel(const _Float16* srcH, const _Float16* srcL,
                                            _Float16* dst, int wave, int lane) {
  gll16(srcH + wave * 512 + lane * 8, dst + wave * 512);
  gll16(srcL + wave * 512 + lane * 8, dst + 4096 + wave * 512);
}

#define MFMA16 __builtin_amdgcn_mfma_f32_16x16x32_f16

extern "C" __global__ void __launch_bounds__(NT, 1)
ode_kernel(const float* __restrict__ actions, const float* __restrict__ y0,
           const float* __restrict__ b1f, const float* __restrict__ b2f,
           const float* __restrict__ dtp, const _Float16* __restrict__ ws,
           float* __restrict__ out)
{
  // LDS: 32K stage dbuf + 64.5K h planes + 20.5K x planes + 16K y = 133 KB -> 1 block/CU
  __shared__ __align__(16) _Float16 stg[2][8192];       // [buf][hi 128x32 | lo 128x32]
  __shared__ __align__(16) _Float16 hHs[16 * 1032];     // h hi, [m][k] pad 1032
  __shared__ __align__(16) _Float16 hLs[16 * 1032];
  __shared__ __align__(16) _Float16 xHs[16 * 328];      // x hi, [m][k] pad 328 (a|y)
  __shared__ __align__(16) _Float16 xLs[16 * 328];
  __shared__ __align__(16) float    yS[16 * 256];       // fp32 state

  const int tid  = threadIdx.x;
  const int wave = tid >> 6, lane = tid & 63;
  const int l15  = lane & 15, g = (lane >> 4) & 3;
  const int nloc = wave * 16 + l15;                     // column-in-phase, 0..127
  const int b0   = blockIdx.x * BR;
  const float dt = dtp[0];

  const _Float16* w1H = ws + W1H_OFF;
  const _Float16* w1L = ws + W1L_OFF;
  const _Float16* w2H = ws + W2H_OFF;
  const _Float16* w2L = ws + W2L_OFF;

  // hoisted biases (n per lane is fixed per phase)
  float b1r[8], b2r[2];
  #pragma unroll
  for (int i = 0; i < 8; ++i) b1r[i] = b1f[i * 128 + nloc];
  b2r[0] = b2f[nloc]; b2r[1] = b2f[128 + nloc];

  // init y tile + out[:, :, 0]
  #pragma unroll
  for (int it = 0; it < 8; ++it) {
    int o = tid + 512 * it;
    int m = o >> 8, c = o & 255;
    float v = y0[(size_t)(b0 + m) * 256 + c];
    yS[m * 256 + c] = v;
    out[((size_t)((b0 + m) * 256 + c)) * 64] = v;
  }
  __syncthreads();

  v4f aHH = {0.f, 0.f, 0.f, 0.f}, aM = aHH, aLL = aHH;

  for (int t = 0; t < 63; ++t) {
    // ---- x-phase: build x = [a_t | y] as fp16 hi/lo planes
    #pragma unroll
    for (int it = 0; it < 2; ++it) {
      int o = tid + 512 * it;
      int m = o >> 6, k = o & 63;
      float v = actions[(size_t)(b0 + m) * 4096 + (size_t)k * 64 + t];
      _Float16 hh = (_Float16)v;
      xHs[m * 328 + k] = hh;
      xLs[m * 328 + k] = (_Float16)((v - (float)hh) * 2048.f);
    }
    #pragma unroll
    for (int it = 0; it < 8; ++it) {
      int o = tid + 512 * it;
      int m = o >> 8, c = o & 255;
      float v = yS[m * 256 + c];
      _Float16 hh = (_Float16)v;
      xHs[m * 328 + 64 + c] = hh;
      xLs[m * 328 + 64 + c] = (_Float16)((v - (float)hh) * 2048.f);
    }

    // ======== GEMM1: h = tanh(x @ W1 + b1); 8 n-phases x 10 k-steps ========
    stage_panel(w1H, w1L, stg[0], wave, lane);
    __syncthreads();   // x writes visible + panel 0 staged
    int gp = 0;
    for (int ph = 0; ph < 8; ++ph) {
      for (int p = 0; p < 10; ++p, ++gp) {
        const int buf = gp & 1;
        if (gp < 79)
          stage_panel(w1H + (gp + 1) * 4096, w1L + (gp + 1) * 4096,
                      stg[buf ^ 1], wave, lane);
        const int xoff = l15 * 328 + p * 32 + g * 8;
        v8h aH = *(const v8h*)&xHs[xoff];
        v8h aL = *(const v8h*)&xLs[xoff];
        const int boff = nloc * 32 + g * 8;
        v8h bH = *(const v8h*)&stg[buf][boff];
        v8h bL = *(const v8h*)&stg[buf][4096 + boff];
        aHH = MFMA16(aH, bH, aHH, 0, 0, 0);
        aM  = MFMA16(aH, bL, aM , 0, 0, 0);
        aM  = MFMA16(aL, bH, aM , 0, 0, 0);
        aLL = MFMA16(aL, bL, aLL, 0, 0, 0);
        if (p == 9) {
          const int n = ph * 128 + nloc;
          #pragma unroll
          for (int j = 0; j < 4; ++j) {
            float v = aHH[j] + aM[j] * (1.f / 2048.f)
                    + aLL[j] * (1.f / 4194304.f) + b1r[ph];
            float th = tanh_fast(v);
            _Float16 hh = (_Float16)th;
            int m = g * 4 + j;
            hHs[m * 1032 + n] = hh;
            hLs[m * 1032 + n] = (_Float16)((th - (float)hh) * 2048.f);
          }
          aHH = v4f{0.f, 0.f, 0.f, 0.f}; aM = aHH; aLL = aHH;
        }
        __syncthreads();
      }
    }

    // ======== GEMM2: y += dt*(h @ W2 + b2); 2 n-phases x 32 k-steps ========
    stage_panel(w2H, w2L, stg[0], wave, lane);
    __syncthreads();   // h writes visible + panel 0 staged
    for (int p2 = 0; p2 < 64; ++p2) {
      const int buf = p2 & 1;
      if (p2 < 63)
        stage_panel(w2H + (p2 + 1) * 4096, w2L + (p2 + 1) * 4096,
                    stg[buf ^ 1], wave, lane);
      const int p = p2 & 31, ph2 = p2 >> 5;
      const int aoff = l15 * 1032 + p * 32 + g * 8;
      v8h aH = *(const v8h*)&hHs[aoff];
      v8h aL = *(const v8h*)&hLs[aoff];
      const int boff = nloc * 32 + g * 8;
      v8h bH = *(const v8h*)&stg[buf][boff];
      v8h bL = *(const v8h*)&stg[buf][4096 + boff];
      aHH = MFMA16(aH, bH, aHH, 0, 0, 0);
      aM  = MFMA16(aH, bL, aM , 0, 0, 0);
      aM  = MFMA16(aL, bH, aM , 0, 0, 0);
      aLL = MFMA16(aL, bL, aLL, 0, 0, 0);
      if (p == 31) {
        const int n = ph2 * 128 + nloc;
        #pragma unroll
        for (int j = 0; j < 4; ++j) {
          float v = aHH[j] + aM[j] * (1.f / 2048.f)
                  + aLL[j] * (1.f / 4194304.f) + b2r[ph2];
          int m = g * 4 + j;
          float ynew = yS[m * 256 + n] + dt * v;
          yS[m * 256 + n] = ynew;
          out[((size_t)((b0 + m) * 256 + n)) * 64 + (t + 1)] = ynew;
        }
        aHH = v4f{0.f, 0.f, 0.f, 0.f}; aM = aHH; aLL = aHH;
      }
      __syncthreads();
    }
    // next step's x-phase is ordered by the last barrier above
  }
}

extern "C" void kernel_launch(void* const* d_in, const int* in_sizes, int n_in,
                              void* d_out, int out_size, void* d_ws, size_t ws_size,
                              hipStream_t stream) {
  const float* actions = (const float*)d_in[1];
  const float* y0      = (const float*)d_in[2];
  const float* W1      = (const float*)d_in[3];
  const float* b1      = (const float*)d_in[4];
  const float* W2      = (const float*)d_in[5];
  const float* b2      = (const float*)d_in[6];
  const float* dtp     = (const float*)d_in[7];
  float* out = (float*)d_out;
  _Float16* ws = (_Float16*)d_ws;   // needs 2.25 MB

  hipLaunchKernelGGL(conv_kernel, dim3(2304), dim3(256), 0, stream, W1, W2, ws);
  hipLaunchKernelGGL(ode_kernel, dim3(4096 / BR), dim3(NT), 0, stream,
                     actions, y0, b1, b2, dtp, ws, out);
}

// Round 3
// 2995.362 us; speedup vs baseline: 2.4552x; 1.8383x over previous
//
#include <hip/hip_runtime.h>

typedef _Float16 v8h __attribute__((ext_vector_type(8)));
typedef float v4f __attribute__((ext_vector_type(4)));

#define NT 512

// ws half-offsets: fragment-swizzled weight planes
//  W1H [80 gp][8 wave][64 lane][8]   at 0       (327680 halves)
//  W1L                               at 327680
//  W2H [64 p2][8 wave][64 lane][8]   at 655360  (262144 halves)
//  W2L                               at 917504  (total 1179648 halves = 2.25 MB)
//  optional transposed actions (float) at half-offset 1179648 (byte 2359296)
static constexpr size_t ATT_BYTES_NEEDED = 2359296ull + 4096ull * 64 * 64 * 4;

#define MFMA16 __builtin_amdgcn_mfma_f32_16x16x32_f16

__device__ __forceinline__ float tanh_fast(float a) {
  float e = __expf(2.0f * a);          // inf for large a -> +/-1 exactly
  return 1.0f - __fdividef(2.0f, e + 1.0f);
}

// One-shot: split W1,W2 into fp16 hi/lo fragments, linear per (iter, wave, lane).
extern "C" __global__ void conv_w(const float* __restrict__ W1,
                                  const float* __restrict__ W2,
                                  _Float16* __restrict__ ws) {
  int i = blockIdx.x * 256 + threadIdx.x;        // 589824 total
  if (i < 327680) {
    int j = i & 7, lane = (i >> 3) & 63, w = (i >> 9) & 7, gp = i >> 12;
    int g = lane >> 4, l15 = lane & 15;
    int ph = gp / 10, p = gp % 10;
    int k = p * 32 + g * 8 + j, col = ph * 128 + w * 16 + l15;
    float v = W1[k * 1024 + col];
    _Float16 hh = (_Float16)v;
    ws[i] = hh;
    ws[327680 + i] = (_Float16)((v - (float)hh) * 2048.f);
  } else {
    int iq = i - 327680;                          // 262144
    int j = iq & 7, lane = (iq >> 3) & 63, w = (iq >> 9) & 7, p2 = iq >> 12;
    int g = lane >> 4, l15 = lane & 15;
    int p = p2 & 31, ph2 = p2 >> 5;
    int k = p * 32 + g * 8 + j, col = ph2 * 128 + w * 16 + l15;
    float v = W2[k * 256 + col];
    _Float16 hh = (_Float16)v;
    ws[655360 + iq] = hh;
    ws[917504 + iq] = (_Float16)((v - (float)hh) * 2048.f);
  }
}

// One-shot: actions (B,F,T) -> att[(t*4096+b)*64+f] for coalesced in-loop reads.
extern "C" __global__ void conv_a(const float* __restrict__ actions,
                                  float* __restrict__ att) {
  size_t o = (size_t)blockIdx.x * 256 + threadIdx.x;   // 16777216 total
  int f = (int)(o & 63);
  int b = (int)((o >> 6) & 4095);
  int t = (int)(o >> 18);
  att[o] = actions[((size_t)b * 64 + f) * 64 + t];
}

extern "C" __global__ void __launch_bounds__(NT, 1)
ode_kernel(const float* __restrict__ actions, const float* __restrict__ att,
           const float* __restrict__ y0,
           const float* __restrict__ b1f, const float* __restrict__ b2f,
           const float* __restrict__ dtp, const _Float16* __restrict__ ws,
           float* __restrict__ out)
{
  // LDS 92 KB: A-operands + biases only (B streams L2->VGPR, no staging)
  __shared__ __align__(16) _Float16 xHs[16 * 328], xLs[16 * 328];
  __shared__ __align__(16) _Float16 hHs[16 * 1032], hLs[16 * 1032];
  __shared__ float b1s[1024], b2s[256];

  const int tid  = threadIdx.x;
  const int wave = tid >> 6, lane = tid & 63;
  const int l15  = lane & 15, g = lane >> 4;          // g in 0..3
  const int nloc = wave * 16 + l15;
  const int b0   = blockIdx.x * 16;
  const float dt = dtp[0];

  for (int i = tid; i < 1024; i += NT) b1s[i] = b1f[i];
  if (tid < 256) b2s[tid] = b2f[tid];

  // y state in registers: slot (m = g*4+j, n = nloc) in ya, (m, 128+nloc) in yb
  float ya[4], yb[4];
  #pragma unroll
  for (int j = 0; j < 4; ++j) {
    int m = g * 4 + j;
    ya[j] = y0[(size_t)(b0 + m) * 256 + nloc];
    yb[j] = y0[(size_t)(b0 + m) * 256 + 128 + nloc];
    out[((size_t)((b0 + m) * 256 + nloc)) * 64] = ya[j];
    out[((size_t)((b0 + m) * 256 + 128 + nloc)) * 64] = yb[j];
  }

  const _Float16* w1h = ws + (size_t)(wave * 64 + lane) * 8;            // +gp*4096
  const _Float16* w1l = ws + 327680 + (size_t)(wave * 64 + lane) * 8;
  const _Float16* w2h = ws + 655360 + (size_t)(wave * 64 + lane) * 8;   // +p2*4096
  const _Float16* w2l = ws + 917504 + (size_t)(wave * 64 + lane) * 8;

  const int xbase = l15 * 328 + g * 8;
  const int hbase = l15 * 1032 + g * 8;

  for (int t = 0; t < 63; ++t) {
    // ---- x-phase: build x = [a_t | y] fp16 hi/lo planes
    #pragma unroll
    for (int it = 0; it < 2; ++it) {
      int o = tid + NT * it;
      int m = o >> 6, k = o & 63;
      float v = att ? att[((size_t)t * 4096 + b0 + m) * 64 + k]
                    : actions[((size_t)(b0 + m) * 64 + k) * 64 + t];
      _Float16 hh = (_Float16)v;
      xHs[m * 328 + k] = hh;
      xLs[m * 328 + k] = (_Float16)((v - (float)hh) * 2048.f);
    }
    #pragma unroll
    for (int j = 0; j < 4; ++j) {
      int m = g * 4 + j;
      float v0v = ya[j];
      _Float16 h0 = (_Float16)v0v;
      xHs[m * 328 + 64 + nloc] = h0;
      xLs[m * 328 + 64 + nloc] = (_Float16)((v0v - (float)h0) * 2048.f);
      float v1v = yb[j];
      _Float16 h1 = (_Float16)v1v;
      xHs[m * 328 + 192 + nloc] = h1;
      xLs[m * 328 + 192 + nloc] = (_Float16)((v1v - (float)h1) * 2048.f);
    }
    __syncthreads();   // x visible to all waves (and h free from prev GEMM2)

    v8h Bh[8], Bl[8];
    v4f aHH = {0.f, 0.f, 0.f, 0.f}, aM = aHH;

    // ======== GEMM1: h = tanh(x @ W1 + b1); 80 iters, depth-8 reg pipeline ====
    #pragma unroll
    for (int s = 0; s < 8; ++s) {
      Bh[s] = *(const v8h*)(w1h + (size_t)s * 4096);
      Bl[s] = *(const v8h*)(w1l + (size_t)s * 4096);
    }
    #pragma unroll 8
    for (int gp = 0; gp < 80; ++gp) {
      const int s = gp & 7;
      v8h bh = Bh[s], bl = Bl[s];
      if (gp < 72) {
        Bh[s] = *(const v8h*)(w1h + (size_t)(gp + 8) * 4096);
        Bl[s] = *(const v8h*)(w1l + (size_t)(gp + 8) * 4096);
      }
      const int p = gp % 10;
      v8h ah = *(const v8h*)&xHs[xbase + p * 32];
      v8h al = *(const v8h*)&xLs[xbase + p * 32];
      aHH = MFMA16(ah, bh, aHH, 0, 0, 0);
      aM  = MFMA16(ah, bl, aM , 0, 0, 0);
      aM  = MFMA16(al, bh, aM , 0, 0, 0);
      if (p == 9) {
        const int n = (gp / 10) * 128 + nloc;
        const float bb = b1s[n];
        #pragma unroll
        for (int j = 0; j < 4; ++j) {
          float v = aHH[j] + aM[j] * (1.f / 2048.f) + bb;
          float th = tanh_fast(v);
          _Float16 hh = (_Float16)th;
          int m = g * 4 + j;
          hHs[m * 1032 + n] = hh;
          hLs[m * 1032 + n] = (_Float16)((th - (float)hh) * 2048.f);
        }
        aHH = v4f{0.f, 0.f, 0.f, 0.f}; aM = aHH;
      }
    }
    __syncthreads();   // h visible to all waves

    // ======== GEMM2: y += dt*(h @ W2 + b2); 64 iters, depth-8 pipeline ========
    #pragma unroll
    for (int s = 0; s < 8; ++s) {
      Bh[s] = *(const v8h*)(w2h + (size_t)s * 4096);
      Bl[s] = *(const v8h*)(w2l + (size_t)s * 4096);
    }
    #pragma unroll 8
    for (int p2 = 0; p2 < 64; ++p2) {
      const int s = p2 & 7;
      v8h bh = Bh[s], bl = Bl[s];
      if (p2 < 56) {
        Bh[s] = *(const v8h*)(w2h + (size_t)(p2 + 8) * 4096);
        Bl[s] = *(const v8h*)(w2l + (size_t)(p2 + 8) * 4096);
      }
      const int p = p2 & 31;
      v8h ah = *(const v8h*)&hHs[hbase + p * 32];
      v8h al = *(const v8h*)&hLs[hbase + p * 32];
      aHH = MFMA16(ah, bh, aHH, 0, 0, 0);
      aM  = MFMA16(ah, bl, aM , 0, 0, 0);
      aM  = MFMA16(al, bh, aM , 0, 0, 0);
      if (p == 31) {
        const int ph2 = p2 >> 5;                  // uniform branch below keeps
        const int n = ph2 * 128 + nloc;           // y-reg indexing static
        const float bb = b2s[n];
        if (ph2 == 0) {
          #pragma unroll
          for (int j = 0; j < 4; ++j) {
            float v = aHH[j] + aM[j] * (1.f / 2048.f) + bb;
            int m = g * 4 + j;
            float yn = ya[j] + dt * v;
            ya[j] = yn;
            out[((size_t)((b0 + m) * 256 + n)) * 64 + (t + 1)] = yn;
          }
        } else {
          #pragma unroll
          for (int j = 0; j < 4; ++j) {
            float v = aHH[j] + aM[j] * (1.f / 2048.f) + bb;
            int m = g * 4 + j;
            float yn = yb[j] + dt * v;
            yb[j] = yn;
            out[((size_t)((b0 + m) * 256 + n)) * 64 + (t + 1)] = yn;
          }
        }
        aHH = v4f{0.f, 0.f, 0.f, 0.f}; aM = aHH;
      }
    }
    // next x-phase writes x-planes (not touched by GEMM2) and own y regs; the
    // following __syncthreads orders everything else. 2 barriers per step total.
  }
}

extern "C" void kernel_launch(void* const* d_in, const int* in_sizes, int n_in,
                              void* d_out, int out_size, void* d_ws, size_t ws_size,
                              hipStream_t stream) {
  const float* actions = (const float*)d_in[1];
  const float* y0      = (const float*)d_in[2];
  const float* W1      = (const float*)d_in[3];
  const float* b1      = (const float*)d_in[4];
  const float* W2      = (const float*)d_in[5];
  const float* b2      = (const float*)d_in[6];
  const float* dtp     = (const float*)d_in[7];
  float* out = (float*)d_out;
  _Float16* ws = (_Float16*)d_ws;

  const bool use_att = ws_size >= ATT_BYTES_NEEDED;
  float* att = use_att ? (float*)((char*)d_ws + 2359296) : nullptr;

  hipLaunchKernelGGL(conv_w, dim3(2304), dim3(256), 0, stream, W1, W2, ws);
  if (use_att)
    hipLaunchKernelGGL(conv_a, dim3(65536), dim3(256), 0, stream, actions, att);
  hipLaunchKernelGGL(ode_kernel, dim3(256), dim3(NT), 0, stream,
                     actions, att, y0, b1, b2, dtp, ws, out);
}